// Round 7
// baseline (108.225 us; speedup 1.0000x reference)
//
#include <hip/hip_runtime.h>

// Problem constants (from reference)
#define B_DIM 16384
#define IN_FEATURES 8192
#define OUT_FEATURES 1024
#define BLOCK_SIZE 8                     // IN_FEATURES / OUT_FEATURES
#define N_OUT (B_DIM * OUT_FEATURES)     // 16,777,216 outputs
#define N_F4 (B_DIM * IN_FEATURES / 4)   // 33,554,432 float4s of x

#define GRID 2048
#define BLOCK 256
#define NWAVES (GRID * BLOCK / 64)       // 8192 waves
#define F4_PER_WAVE_STEP 256             // 4 KiB per wave per step (4 loads)
#define STEP_F4 (NWAVES * F4_PER_WAVE_STEP)   // 2,097,152 f4/step (mult of 2048)
#define OUT_PER_STEP (STEP_F4 / 2)       // 1,048,576 outputs/step
#define N_STEPS (N_F4 / STEP_F4)         // 16, exact (even)

// Native clang vector type — __builtin_nontemporal_load/store accept these.
typedef float f32x4 __attribute__((ext_vector_type(4)));

// Wave-cooperative streaming kernel, software-pipelined so that NEXT-step
// loads are issued BEFORE current-step stores. Rationale: vmcnt is a single
// in-order counter shared by loads and stores; if stores(s) precede loads(s+1)
// in the VMEM queue, consuming loads(s+1) waits for the (slow) nontemporal
// store acks. Issuing loads first makes load consumption independent of store
// completion. Two NAMED buffers + fully unrolled even/odd steps keep all
// array indices compile-time (no scratch).
__global__ __launch_bounds__(BLOCK) void blocklinear_pipe_kernel(
        const float* __restrict__ x,
        const float* __restrict__ lw,
        float* __restrict__ y) {
    const int tid  = blockIdx.x * BLOCK + threadIdx.x;
    const int lane = threadIdx.x & 63;
    const int wave = tid >> 6;                 // global wave id [0, NWAVES)

    const f32x4* x4  = (const f32x4*)x;
    const f32x4* lw4 = (const f32x4*)lw;      // 2048 f4 = 32 KiB, cache-resident

    // Loop-invariant weight fragments (one-time exp), 4 float4s per lane.
    // Window: (wave*256 mod 2048) + 192 + 63 <= 2047 — no wrap.
    const int wi0 = (wave * F4_PER_WAVE_STEP + lane) & 2047;
    f32x4 w[4];
    #pragma unroll
    for (int j = 0; j < 4; ++j) {
        const f32x4 l = lw4[wi0 + j * 64];
        w[j].x = expf(l.x); w[j].y = expf(l.y);
        w[j].z = expf(l.z); w[j].w = expf(l.w);
    }

    const size_t base0 = (size_t)wave * F4_PER_WAVE_STEP;
    const int    ob0   = wave * (F4_PER_WAVE_STEP / 2);
    const bool storer = ((lane & 1) == 0);
    const int  m = lane >> 1;                       // [0,32)

    f32x4 bufA[4], bufB[4];

#define LOAD_STEP(buf, s) do {                                               \
        const size_t b_ = base0 + (size_t)(s) * STEP_F4;                     \
        _Pragma("unroll")                                                    \
        for (int j = 0; j < 4; ++j)                                          \
            buf[j] = __builtin_nontemporal_load(&x4[b_ + j * 64 + lane]);    \
    } while (0)

#define PROC_STEP(buf, s) do {                                               \
        const int ob_ = ob0 + (s) * OUT_PER_STEP;                            \
        _Pragma("unroll")                                                    \
        for (int j = 0; j < 4; ++j) {                                        \
            const float p_ = buf[j].x * w[j].x + buf[j].y * w[j].y           \
                           + buf[j].z * w[j].z + buf[j].w * w[j].w;          \
            const float s_ = p_ + __shfl_xor(p_, 1, 64);                     \
            if (storer)                                                      \
                __builtin_nontemporal_store(s_, &y[ob_ + j * 32 + m]);       \
        }                                                                    \
    } while (0)

    // Prologue: loads for step 0.
    LOAD_STEP(bufA, 0);

    // Steady state: issue loads for s+1 BEFORE the stores of step s.
    #pragma unroll
    for (int s = 0; s < N_STEPS; s += 2) {
        LOAD_STEP(bufB, s + 1);          // loads ahead of bufA's stores
        PROC_STEP(bufA, s);
        if (s + 2 < N_STEPS)
            LOAD_STEP(bufA, s + 2);      // loads ahead of bufB's stores
        PROC_STEP(bufB, s + 1);
    }

#undef LOAD_STEP
#undef PROC_STEP
}

extern "C" void kernel_launch(void* const* d_in, const int* in_sizes, int n_in,
                              void* d_out, int out_size, void* d_ws, size_t ws_size,
                              hipStream_t stream) {
    const float* x = (const float*)d_in[0];          // [B, IN_FEATURES] f32
    const float* log_weight = (const float*)d_in[1]; // [OUT_FEATURES, 8] f32
    float* y = (float*)d_out;                        // [B, OUT_FEATURES] f32

    blocklinear_pipe_kernel<<<GRID, BLOCK, 0, stream>>>(x, log_weight, y);
}